// Round 8
// baseline (282.554 us; speedup 1.0000x reference)
//
#include <hip/hip_runtime.h>

#define HID 128

typedef unsigned short ushort_t;
typedef unsigned int uint_t;
typedef unsigned long long ull_t;
typedef float f32x4 __attribute__((ext_vector_type(4)));
typedef short s16x8 __attribute__((ext_vector_type(8)));

__device__ __forceinline__ ushort_t f2bf(float f) {
  uint_t u = __float_as_uint(f);
  uint_t r = (u + 0x7FFFu + ((u >> 16) & 1u)) >> 16;  // RNE
  return (ushort_t)r;
}
__device__ __forceinline__ float bfLo(uint_t v) { return __uint_as_float(v << 16); }
__device__ __forceinline__ float bfHi(uint_t v) { return __uint_as_float(v & 0xFFFF0000u); }

__device__ __forceinline__ uint4 pack8(const float4& lo, const float4& hi) {
  uint4 p;
  p.x = (uint_t)f2bf(lo.x) | ((uint_t)f2bf(lo.y) << 16);
  p.y = (uint_t)f2bf(lo.z) | ((uint_t)f2bf(lo.w) << 16);
  p.z = (uint_t)f2bf(hi.x) | ((uint_t)f2bf(hi.y) << 16);
  p.w = (uint_t)f2bf(hi.z) | ((uint_t)f2bf(hi.w) << 16);
  return p;
}

// ------- fused prep: 8-deep gather + weight-swizzle + degree count -------
// R9: 1-deep = 43us. R12: 4-deep = 40.8us @ 54% occ. R15: 8-deep = 40.2us
// @ 36% occ -- ILP gain cancelled by VGPR/occupancy loss. Prep is pinned
// ~40us (emb reads are L3-hits; surplus WRITE is degcount atomic RMW).
// R14 lesson: no grid.sync fusion (coop barrier ~100us/sync on 8 XCDs).
__global__ __launch_bounds__(256) void prep_kernel(
    const float* __restrict__ emb, const int* __restrict__ x,
    ushort_t* __restrict__ hb, int N,
    const float* __restrict__ Wl1, const float* __restrict__ Wr1,
    const float* __restrict__ Wl2, const float* __restrict__ Wr2,
    ushort_t* __restrict__ wsw,
    const int* __restrict__ dst, int* __restrict__ deg, int E) {
  int tid = blockIdx.x * 256 + threadIdx.x;
  const int eN = (N + 7) >> 3;
  int gthreads = eN * 16;
  if (tid < gthreads) {
    int r0 = tid >> 4, j = (tid & 15) * 8;
    int rs[8], si[8];
#pragma unroll
    for (int k = 0; k < 8; k++) {
      int r = r0 + k * eN;
      rs[k] = r;
      int rc = (r < N) ? r : N - 1;
      si[k] = x[rc];  // 8 independent loads
    }
    float4 lo[8], hi[8];
#pragma unroll
    for (int k = 0; k < 8; k++) {
      const float* pk = &emb[(size_t)si[k] * HID + j];
      lo[k] = *(const float4*)pk;
      hi[k] = *(const float4*)(pk + 4);
    }
#pragma unroll
    for (int k = 0; k < 8; k++) {
      if (rs[k] < N)
        *(uint4*)&hb[(size_t)rs[k] * HID + j] = pack8(lo[k], hi[k]);
    }
    return;
  }
  tid -= gthreads;
  if (tid < 65536) {
    const float* srcs[4] = {Wl1, Wr1, Wl2, Wr2};
    int m = tid >> 14, idx = tid & 16383;
    int j = idx & 7;
    int lane = (idx >> 3) & 63;
    int nt = (idx >> 9) & 7;
    int ks = (idx >> 12) & 3;
    int row = nt * 16 + (lane & 15);
    int col = ks * 32 + (lane >> 4) * 8 + j;
    wsw[tid] = f2bf(srcs[m][row * HID + col]);
    return;
  }
  tid -= 65536;
  if (tid < E) atomicAdd(&deg[dst[tid]], 1);
}

// ------- fused CSR scan: decoupled lookback, ONE dispatch (R18) -------
// Replaces scan1+scan3. 98 blocks x 256t, 4 nodes/thread. All blocks are
// trivially co-resident (392 waves << capacity) -> spin-wait is safe under
// ANY dispatch order. Cross-block handoff via device-scope 64-bit atomics:
// partials[b] = state<<32 | sum; state 0=invalid (memset), 1=aggregate,
// 2=inclusive-prefix. Memset covers partials (poison would fake state!).
__global__ __launch_bounds__(256) void scan_kernel(
    const int* __restrict__ deg, int* __restrict__ offsets,
    int* __restrict__ cursor, ull_t* __restrict__ partials, int N, int E) {
  __shared__ int s[256];
  __shared__ int sPrefix;
  int b = blockIdx.x, t = threadIdx.x;
  int base = b * 1024 + t * 4;
  int v0 = 0, v1 = 0, v2 = 0, v3 = 0;
  if (base + 0 < N) v0 = deg[base + 0];
  if (base + 1 < N) v1 = deg[base + 1];
  if (base + 2 < N) v2 = deg[base + 2];
  if (base + 3 < N) v3 = deg[base + 3];
  int mySum = v0 + v1 + v2 + v3;
  s[t] = mySum;
  __syncthreads();
  for (int off = 1; off < 256; off <<= 1) {
    int v = (t >= off) ? s[t - off] : 0;
    __syncthreads();
    s[t] += v;
    __syncthreads();
  }
  int excl = s[t] - mySum;
  int blockSum = s[255];

  if (t == 0) {
    // publish aggregate ASAP so successors can progress
    ull_t st = (b == 0) ? 2ull : 1ull;
    __hip_atomic_store(&partials[b], (st << 32) | (uint_t)blockSum,
                       __ATOMIC_RELEASE, __HIP_MEMORY_SCOPE_AGENT);
    int prefix = 0;
    if (b > 0) {
      int idx = b - 1;
      while (true) {
        ull_t v = __hip_atomic_load(&partials[idx], __ATOMIC_ACQUIRE,
                                    __HIP_MEMORY_SCOPE_AGENT);
        uint_t state = (uint_t)(v >> 32);
        if (state == 0) continue;  // predecessor not published yet
        prefix += (int)(uint_t)v;
        if (state == 2) break;     // found an inclusive entry
        idx--;
      }
      __hip_atomic_store(&partials[b],
                         (2ull << 32) | (uint_t)(prefix + blockSum),
                         __ATOMIC_RELEASE, __HIP_MEMORY_SCOPE_AGENT);
    }
    sPrefix = prefix;
  }
  __syncthreads();
  int prefix = sPrefix;

  int e0 = prefix + excl;
  if (base + 0 < N) { offsets[base + 0] = e0;            cursor[base + 0] = e0; }
  if (base + 1 < N) { offsets[base + 1] = e0 + v0;       cursor[base + 1] = e0 + v0; }
  if (base + 2 < N) { offsets[base + 2] = e0 + v0 + v1;  cursor[base + 2] = e0 + v0 + v1; }
  if (base + 3 < N) { offsets[base + 3] = e0 + v0 + v1 + v2;
                      cursor[base + 3] = e0 + v0 + v1 + v2; }
  if (b == 0 && t == 0) offsets[N] = E;
}

__global__ __launch_bounds__(256) void fill_kernel(
    const int* __restrict__ src, const int* __restrict__ dst,
    int* __restrict__ cursor, int* __restrict__ csr, int E) {
  int e = blockIdx.x * 256 + threadIdx.x;
  if (e >= E) return;
  int d = dst[e];
  int pos = atomicAdd(&cursor[d], 1);
  csr[pos] = src[e];
}

// ------- aggregate: one node per QUARTER-wave, masked 8-deep batch -------
// R11: gather-latency-bound, needs MAX occupancy -> standalone kernel.
// R13: masked 8-wide batch finishes deg<=8 (~85% at Poisson(6)) in ONE
// dependent csr->hb round. R17: XCD swizzle removed (falsified in R6: L2
// does not survive dispatch boundaries; scattering hurt locality).
__global__ __launch_bounds__(256) void aggregate_kernel(
    const ushort_t* __restrict__ hb, const int* __restrict__ offsets,
    const int* __restrict__ csr, ushort_t* __restrict__ meanb, int N) {
  int t = threadIdx.x;
  int node = blockIdx.x * 16 + (t >> 4);
  if (node >= N) return;
  int l15 = t & 15;
  int o0 = offsets[node], o1 = offsets[node + 1];
  int last = o1 - 1;

  float acc[8];
#pragma unroll
  for (int i = 0; i < 8; i++) acc[i] = 0.f;

  for (int e = o0; e < o1; e += 8) {
    uint4 v[8];
    float m[8];
#pragma unroll
    for (int i = 0; i < 8; i++) {
      int idx = e + i;
      bool val = idx < o1;
      int sidx = csr[val ? idx : last];
      v[i] = *(const uint4*)&hb[(size_t)sidx * HID + l15 * 8];
      m[i] = val ? 1.f : 0.f;
    }
#pragma unroll
    for (int i = 0; i < 8; i++) {
      acc[0] = fmaf(m[i], bfLo(v[i].x), acc[0]);
      acc[1] = fmaf(m[i], bfHi(v[i].x), acc[1]);
      acc[2] = fmaf(m[i], bfLo(v[i].y), acc[2]);
      acc[3] = fmaf(m[i], bfHi(v[i].y), acc[3]);
      acc[4] = fmaf(m[i], bfLo(v[i].z), acc[4]);
      acc[5] = fmaf(m[i], bfHi(v[i].z), acc[5]);
      acc[6] = fmaf(m[i], bfLo(v[i].w), acc[6]);
      acc[7] = fmaf(m[i], bfHi(v[i].w), acc[7]);
    }
  }

  int d = o1 - o0;
  float inv = 1.0f / (float)(d > 1 ? d : 1);
  uint4 p;
  p.x = (uint_t)f2bf(acc[0] * inv) | ((uint_t)f2bf(acc[1] * inv) << 16);
  p.y = (uint_t)f2bf(acc[2] * inv) | ((uint_t)f2bf(acc[3] * inv) << 16);
  p.z = (uint_t)f2bf(acc[4] * inv) | ((uint_t)f2bf(acc[5] * inv) << 16);
  p.w = (uint_t)f2bf(acc[6] * inv) | ((uint_t)f2bf(acc[7] * inv) << 16);
  *(uint4*)&meanb[(size_t)node * HID + l15 * 8] = p;
}

// ---------------- MFMA GEMM: out = relu(mean@Wl^T + h@Wr^T + b) ----------------
// R13 lesson: single 64KB stage, ONE sync (both matrices' loads in flight).
// R15 lesson: never trade wave count for per-wave tiles (latency-bound).
// R17 (confirmed): 512-thread blocks -- LDS binds at 2 blk/CU either way,
// so 8 waves/block doubles resident waves to 16/CU. gemm left top-5.
__global__ __launch_bounds__(512, 4) void mfma_gemm_kernel(
    const ushort_t* __restrict__ meanb, const ushort_t* __restrict__ hb,
    const ushort_t* __restrict__ WlS, const ushort_t* __restrict__ WrS,
    const float* __restrict__ bias, float* __restrict__ outF,
    ushort_t* __restrict__ outB, int N, int outIsBf16) {
  __shared__ ushort_t ws[32768];  // 64 KB: [0..16383]=Wl frags, rest = Wr
  const int t = threadIdx.x;
  const int wave = t >> 6;   // 0..7
  const int lane = t & 63;
  const int rowBase = (blockIdx.x * 8 + wave) * 32;
  const int l15 = lane & 15;
  const int quad = lane >> 4;
  const int kq = quad * 8;
  const bool active = rowBase < N;

  int r0 = rowBase + l15;       if (r0 >= N) r0 = N - 1;
  int r1 = rowBase + 16 + l15;  if (r1 >= N) r1 = N - 1;

  // A-frag prefetch (independent of LDS staging)
  s16x8 a[2][2][4];  // [half][rowgrp][ks]
  if (active) {
#pragma unroll
    for (int ks = 0; ks < 4; ks++) {
      a[0][0][ks] = *(const s16x8*)&meanb[(size_t)r0 * HID + ks * 32 + kq];
      a[0][1][ks] = *(const s16x8*)&meanb[(size_t)r1 * HID + ks * 32 + kq];
      a[1][0][ks] = *(const s16x8*)&hb[(size_t)r0 * HID + ks * 32 + kq];
      a[1][1][ks] = *(const s16x8*)&hb[(size_t)r1 * HID + ks * 32 + kq];
    }
  }

  // stage both weight matrices: contiguous 16B per thread, coalesced
#pragma unroll
  for (int it = 0; it < 4; it++) {
    int o = (it * 512 + t) * 8;
    *(s16x8*)&ws[o] = *(const s16x8*)&WlS[o];
    *(s16x8*)&ws[16384 + o] = *(const s16x8*)&WrS[o];
  }
  __syncthreads();

  if (active) {
    f32x4 acc[2][8];
#pragma unroll
    for (int mt = 0; mt < 2; mt++)
#pragma unroll
      for (int nt = 0; nt < 8; nt++) acc[mt][nt] = (f32x4){0.f, 0.f, 0.f, 0.f};

#pragma unroll
    for (int half = 0; half < 2; half++) {
      const int hbase = half * 16384;
#pragma unroll
      for (int ks = 0; ks < 4; ks++)
#pragma unroll
        for (int nt = 0; nt < 8; nt++) {
          s16x8 bfrag = *(const s16x8*)&ws[hbase + ((ks * 8 + nt) * 64 + lane) * 8];
          acc[0][nt] = __builtin_amdgcn_mfma_f32_16x16x32_bf16(a[half][0][ks], bfrag, acc[0][nt], 0, 0, 0);
          acc[1][nt] = __builtin_amdgcn_mfma_f32_16x16x32_bf16(a[half][1][ks], bfrag, acc[1][nt], 0, 0, 0);
        }
    }

#pragma unroll
    for (int mt = 0; mt < 2; mt++) {
#pragma unroll
      for (int nt = 0; nt < 8; nt++) {
        int col = nt * 16 + l15;
        float bv = bias[col];
#pragma unroll
        for (int r = 0; r < 4; r++) {
          int row = rowBase + mt * 16 + quad * 4 + r;
          if (row < N) {
            float v = fmaxf(acc[mt][nt][r] + bv, 0.f);
            if (outIsBf16) outB[(size_t)row * HID + col] = f2bf(v);
            else           outF[(size_t)row * HID + col] = v;
          }
        }
      }
    }
  }
}

extern "C" void kernel_launch(void* const* d_in, const int* in_sizes, int n_in,
                              void* d_out, int out_size, void* d_ws, size_t ws_size,
                              hipStream_t stream) {
  const int* x = (const int*)d_in[0];
  const int* ei = (const int*)d_in[1];
  const float* emb = (const float*)d_in[2];
  const float* Wl1 = (const float*)d_in[3];
  const float* bl1 = (const float*)d_in[4];
  const float* Wr1 = (const float*)d_in[5];
  const float* Wl2 = (const float*)d_in[6];
  const float* bl2 = (const float*)d_in[7];
  const float* Wr2 = (const float*)d_in[8];
  float* out = (float*)d_out;

  const int N = in_sizes[0];
  const int E = in_sizes[1] / 2;
  const int* srcI = ei;
  const int* dstI = ei + E;

  // workspace layout (deg and partials CONTIGUOUS: one memset covers both)
  char* p = (char*)d_ws;
  ushort_t* hb = (ushort_t*)p;    p += (size_t)N * HID * sizeof(ushort_t);
  ushort_t* hb2 = (ushort_t*)p;   p += (size_t)N * HID * sizeof(ushort_t);
  ushort_t* meanb = (ushort_t*)p; p += (size_t)N * HID * sizeof(ushort_t);
  ushort_t* wb = (ushort_t*)p;    p += (size_t)4 * 16384 * sizeof(ushort_t);
  int* deg = (int*)p;             p += (size_t)((N + 3) & ~3) * sizeof(int);
  ull_t* partials = (ull_t*)p;    p += 128 * sizeof(ull_t);
  int* offsets = (int*)p;         p += (size_t)((N + 4) & ~3) * sizeof(int);
  int* cursor = (int*)p;          p += (size_t)((N + 3) & ~3) * sizeof(int);
  int* csr = (int*)p;             p += (size_t)((E + 3) & ~3) * sizeof(int);

  ushort_t* Wlb1 = wb;
  ushort_t* Wrb1 = wb + 16384;
  ushort_t* Wlb2 = wb + 32768;
  ushort_t* Wrb2 = wb + 49152;

  const int nScanBlocks = (N + 1023) / 1024;  // 98 <= 128 partial slots
  const int eBlocks = (E + 255) / 256;
  const int gemmBlocks = (N + 255) / 256;     // 512 threads, 256 rows/block
  const int aggBlocks = (N + 15) / 16;
  const int eN = (N + 7) / 8;
  const int prepBlocks = (eN * 16 + 65536 + E + 255) / 256;
  const size_t zeroBytes = (size_t)((N + 3) & ~3) * sizeof(int)
                         + 128 * sizeof(ull_t);

  // ---- CSR build + conversions (memset covers deg AND partials) ----
  hipMemsetAsync(deg, 0, zeroBytes, stream);
  prep_kernel<<<prepBlocks, 256, 0, stream>>>(emb, x, hb, N,
                                              Wl1, Wr1, Wl2, Wr2, wb,
                                              dstI, deg, E);
  scan_kernel<<<nScanBlocks, 256, 0, stream>>>(deg, offsets, cursor,
                                               partials, N, E);
  fill_kernel<<<eBlocks, 256, 0, stream>>>(srcI, dstI, cursor, csr, E);

  // ---- layer 1: hb -> hb2 (bf16) ----
  aggregate_kernel<<<aggBlocks, 256, 0, stream>>>(hb, offsets, csr, meanb, N);
  mfma_gemm_kernel<<<gemmBlocks, 512, 0, stream>>>(meanb, hb, Wlb1, Wrb1, bl1,
                                                   nullptr, hb2, N, 1);

  // ---- layer 2: hb2 -> out (f32) ----
  aggregate_kernel<<<aggBlocks, 256, 0, stream>>>(hb2, offsets, csr, meanb, N);
  mfma_gemm_kernel<<<gemmBlocks, 512, 0, stream>>>(meanb, hb2, Wlb2, Wrb2, bl2,
                                                   out, nullptr, N, 0);
}

// Round 9
// 273.423 us; speedup vs baseline: 1.0334x; 1.0334x over previous
//
#include <hip/hip_runtime.h>

#define HID 128

typedef unsigned short ushort_t;
typedef unsigned int uint_t;
typedef unsigned long long ull_t;
typedef float f32x4 __attribute__((ext_vector_type(4)));
typedef short s16x8 __attribute__((ext_vector_type(8)));

__device__ __forceinline__ ushort_t f2bf(float f) {
  uint_t u = __float_as_uint(f);
  uint_t r = (u + 0x7FFFu + ((u >> 16) & 1u)) >> 16;  // RNE
  return (ushort_t)r;
}
__device__ __forceinline__ float bfLo(uint_t v) { return __uint_as_float(v << 16); }
__device__ __forceinline__ float bfHi(uint_t v) { return __uint_as_float(v & 0xFFFF0000u); }

__device__ __forceinline__ uint4 pack8(const float4& lo, const float4& hi) {
  uint4 p;
  p.x = (uint_t)f2bf(lo.x) | ((uint_t)f2bf(lo.y) << 16);
  p.y = (uint_t)f2bf(lo.z) | ((uint_t)f2bf(lo.w) << 16);
  p.z = (uint_t)f2bf(hi.x) | ((uint_t)f2bf(hi.y) << 16);
  p.w = (uint_t)f2bf(hi.z) | ((uint_t)f2bf(hi.w) << 16);
  return p;
}

// ------- fused prep: 8-deep gather + weight-swizzle + degree count -------
// R9: 1-deep = 43us. R12: 4-deep = 40.8us @ 54% occ. R15: 8-deep = 40.2us
// @ 36% occ -- ILP gain cancelled by VGPR/occupancy loss. Prep pinned ~40us.
// R14 lesson: no grid.sync fusion (coop barrier ~100us/sync on 8 XCDs).
__global__ __launch_bounds__(256) void prep_kernel(
    const float* __restrict__ emb, const int* __restrict__ x,
    ushort_t* __restrict__ hb, int N,
    const float* __restrict__ Wl1, const float* __restrict__ Wr1,
    const float* __restrict__ Wl2, const float* __restrict__ Wr2,
    ushort_t* __restrict__ wsw,
    const int* __restrict__ dst, int* __restrict__ deg, int E) {
  int tid = blockIdx.x * 256 + threadIdx.x;
  const int eN = (N + 7) >> 3;
  int gthreads = eN * 16;
  if (tid < gthreads) {
    int r0 = tid >> 4, j = (tid & 15) * 8;
    int rs[8], si[8];
#pragma unroll
    for (int k = 0; k < 8; k++) {
      int r = r0 + k * eN;
      rs[k] = r;
      int rc = (r < N) ? r : N - 1;
      si[k] = x[rc];  // 8 independent loads
    }
    float4 lo[8], hi[8];
#pragma unroll
    for (int k = 0; k < 8; k++) {
      const float* pk = &emb[(size_t)si[k] * HID + j];
      lo[k] = *(const float4*)pk;
      hi[k] = *(const float4*)(pk + 4);
    }
#pragma unroll
    for (int k = 0; k < 8; k++) {
      if (rs[k] < N)
        *(uint4*)&hb[(size_t)rs[k] * HID + j] = pack8(lo[k], hi[k]);
    }
    return;
  }
  tid -= gthreads;
  if (tid < 65536) {
    const float* srcs[4] = {Wl1, Wr1, Wl2, Wr2};
    int m = tid >> 14, idx = tid & 16383;
    int j = idx & 7;
    int lane = (idx >> 3) & 63;
    int nt = (idx >> 9) & 7;
    int ks = (idx >> 12) & 3;
    int row = nt * 16 + (lane & 15);
    int col = ks * 32 + (lane >> 4) * 8 + j;
    wsw[tid] = f2bf(srcs[m][row * HID + col]);
    return;
  }
  tid -= 65536;
  if (tid < E) atomicAdd(&deg[dst[tid]], 1);
}

// ------- fused CSR scan: decoupled lookback, WAVE-PARALLEL (R19) -------
// R18 lesson: serial lookback (t==0 walks b-1 predecessors, ~0.5us/atomic
// load through the coherence point) cost more than the dispatch gap it
// saved. Wave 0's 64 lanes now load 64 predecessors AT ONCE; ballots find
// the nearest state-2 entry and validate no state-0 holes; shuffle-reduce
// sums the window. 98 blocks -> <=2 rounds. partials[b]=state<<32|sum;
// state 0=invalid (covered by the deg memset), 1=aggregate, 2=inclusive.
__global__ __launch_bounds__(256) void scan_kernel(
    const int* __restrict__ deg, int* __restrict__ offsets,
    int* __restrict__ cursor, ull_t* __restrict__ partials, int N, int E) {
  __shared__ int s[256];
  __shared__ int sPrefix;
  int b = blockIdx.x, t = threadIdx.x;
  int base = b * 1024 + t * 4;
  int v0 = 0, v1 = 0, v2 = 0, v3 = 0;
  if (base + 0 < N) v0 = deg[base + 0];
  if (base + 1 < N) v1 = deg[base + 1];
  if (base + 2 < N) v2 = deg[base + 2];
  if (base + 3 < N) v3 = deg[base + 3];
  int mySum = v0 + v1 + v2 + v3;
  s[t] = mySum;
  __syncthreads();
  for (int off = 1; off < 256; off <<= 1) {
    int v = (t >= off) ? s[t - off] : 0;
    __syncthreads();
    s[t] += v;
    __syncthreads();
  }
  int excl = s[t] - mySum;
  int blockSum = s[255];

  if (b == 0) {
    if (t == 0) {
      __hip_atomic_store(&partials[0], (2ull << 32) | (uint_t)blockSum,
                         __ATOMIC_RELEASE, __HIP_MEMORY_SCOPE_AGENT);
      sPrefix = 0;
    }
  } else if (t < 64) {
    if (t == 0)
      __hip_atomic_store(&partials[b], (1ull << 32) | (uint_t)blockSum,
                         __ATOMIC_RELEASE, __HIP_MEMORY_SCOPE_AGENT);
    int windowEnd = b - 1;
    int sum = 0;
    bool done = false;
    while (!done) {
      int idx = windowEnd - t;
      ull_t v = (idx >= 0)
          ? __hip_atomic_load(&partials[idx], __ATOMIC_ACQUIRE,
                              __HIP_MEMORY_SCOPE_AGENT)
          : (1ull << 32);  // below block 0: neutral (state1, value 0)
      uint_t st = (uint_t)(v >> 32);
      ull_t ball2 = __ballot(st == 2);
      ull_t ball0 = __ballot(st == 0);
      if (ball2 != 0) {
        int pl = __ffsll((unsigned long long)ball2) - 1;  // nearest state-2
        ull_t below = (pl == 0) ? 0ull : ((1ull << pl) - 1ull);
        if ((ball0 & below) == 0) {  // no unpublished holes before it
          int contrib = (t <= (uint_t)pl) ? (int)(uint_t)v : 0;
#pragma unroll
          for (int off = 32; off > 0; off >>= 1)
            contrib += __shfl_down(contrib, off, 64);
          sum += __shfl(contrib, 0, 64);
          done = true;
        }
      } else if (ball0 == 0) {
        // whole window is aggregates: take it and slide back
        int contrib = (int)(uint_t)v;
#pragma unroll
        for (int off = 32; off > 0; off >>= 1)
          contrib += __shfl_down(contrib, off, 64);
        sum += __shfl(contrib, 0, 64);
        windowEnd -= 64;
      }
      // else: holes but no state-2 yet -> retry
    }
    if (t == 0) {
      __hip_atomic_store(&partials[b],
                         (2ull << 32) | (uint_t)(sum + blockSum),
                         __ATOMIC_RELEASE, __HIP_MEMORY_SCOPE_AGENT);
      sPrefix = sum;
    }
  }
  __syncthreads();
  int prefix = sPrefix;

  int e0 = prefix + excl;
  if (base + 0 < N) { offsets[base + 0] = e0;            cursor[base + 0] = e0; }
  if (base + 1 < N) { offsets[base + 1] = e0 + v0;       cursor[base + 1] = e0 + v0; }
  if (base + 2 < N) { offsets[base + 2] = e0 + v0 + v1;  cursor[base + 2] = e0 + v0 + v1; }
  if (base + 3 < N) { offsets[base + 3] = e0 + v0 + v1 + v2;
                      cursor[base + 3] = e0 + v0 + v1 + v2; }
  if (b == 0 && t == 0) offsets[N] = E;
}

__global__ __launch_bounds__(256) void fill_kernel(
    const int* __restrict__ src, const int* __restrict__ dst,
    int* __restrict__ cursor, int* __restrict__ csr, int E) {
  int e = blockIdx.x * 256 + threadIdx.x;
  if (e >= E) return;
  int d = dst[e];
  int pos = atomicAdd(&cursor[d], 1);
  csr[pos] = src[e];
}

// ------- aggregate: one node per QUARTER-wave, masked 8-deep batch -------
// R11: gather-latency-bound, needs MAX occupancy -> standalone kernel.
// R13: masked 8-wide batch finishes deg<=8 (~85% at Poisson(6)) in ONE
// dependent csr->hb round. R17: XCD swizzle removed (falsified in R6).
__global__ __launch_bounds__(256) void aggregate_kernel(
    const ushort_t* __restrict__ hb, const int* __restrict__ offsets,
    const int* __restrict__ csr, ushort_t* __restrict__ meanb, int N) {
  int t = threadIdx.x;
  int node = blockIdx.x * 16 + (t >> 4);
  if (node >= N) return;
  int l15 = t & 15;
  int o0 = offsets[node], o1 = offsets[node + 1];
  int last = o1 - 1;

  float acc[8];
#pragma unroll
  for (int i = 0; i < 8; i++) acc[i] = 0.f;

  for (int e = o0; e < o1; e += 8) {
    uint4 v[8];
    float m[8];
#pragma unroll
    for (int i = 0; i < 8; i++) {
      int idx = e + i;
      bool val = idx < o1;
      int sidx = csr[val ? idx : last];
      v[i] = *(const uint4*)&hb[(size_t)sidx * HID + l15 * 8];
      m[i] = val ? 1.f : 0.f;
    }
#pragma unroll
    for (int i = 0; i < 8; i++) {
      acc[0] = fmaf(m[i], bfLo(v[i].x), acc[0]);
      acc[1] = fmaf(m[i], bfHi(v[i].x), acc[1]);
      acc[2] = fmaf(m[i], bfLo(v[i].y), acc[2]);
      acc[3] = fmaf(m[i], bfHi(v[i].y), acc[3]);
      acc[4] = fmaf(m[i], bfLo(v[i].z), acc[4]);
      acc[5] = fmaf(m[i], bfHi(v[i].z), acc[5]);
      acc[6] = fmaf(m[i], bfLo(v[i].w), acc[6]);
      acc[7] = fmaf(m[i], bfHi(v[i].w), acc[7]);
    }
  }

  int d = o1 - o0;
  float inv = 1.0f / (float)(d > 1 ? d : 1);
  uint4 p;
  p.x = (uint_t)f2bf(acc[0] * inv) | ((uint_t)f2bf(acc[1] * inv) << 16);
  p.y = (uint_t)f2bf(acc[2] * inv) | ((uint_t)f2bf(acc[3] * inv) << 16);
  p.z = (uint_t)f2bf(acc[4] * inv) | ((uint_t)f2bf(acc[5] * inv) << 16);
  p.w = (uint_t)f2bf(acc[6] * inv) | ((uint_t)f2bf(acc[7] * inv) << 16);
  *(uint4*)&meanb[(size_t)node * HID + l15 * 8] = p;
}

// ---------------- MFMA GEMM: out = relu(mean@Wl^T + h@Wr^T + b) ----------------
// R13 lesson: single 64KB stage, ONE sync (both matrices' loads in flight).
// R15 lesson: never trade wave count for per-wave tiles (latency-bound).
// R17 (confirmed): 512-thread blocks -- LDS binds at 2 blk/CU either way,
// so 8 waves/block doubles resident waves to 16/CU. gemm left top-5.
__global__ __launch_bounds__(512, 4) void mfma_gemm_kernel(
    const ushort_t* __restrict__ meanb, const ushort_t* __restrict__ hb,
    const ushort_t* __restrict__ WlS, const ushort_t* __restrict__ WrS,
    const float* __restrict__ bias, float* __restrict__ outF,
    ushort_t* __restrict__ outB, int N, int outIsBf16) {
  __shared__ ushort_t ws[32768];  // 64 KB: [0..16383]=Wl frags, rest = Wr
  const int t = threadIdx.x;
  const int wave = t >> 6;   // 0..7
  const int lane = t & 63;
  const int rowBase = (blockIdx.x * 8 + wave) * 32;
  const int l15 = lane & 15;
  const int quad = lane >> 4;
  const int kq = quad * 8;
  const bool active = rowBase < N;

  int r0 = rowBase + l15;       if (r0 >= N) r0 = N - 1;
  int r1 = rowBase + 16 + l15;  if (r1 >= N) r1 = N - 1;

  // A-frag prefetch (independent of LDS staging)
  s16x8 a[2][2][4];  // [half][rowgrp][ks]
  if (active) {
#pragma unroll
    for (int ks = 0; ks < 4; ks++) {
      a[0][0][ks] = *(const s16x8*)&meanb[(size_t)r0 * HID + ks * 32 + kq];
      a[0][1][ks] = *(const s16x8*)&meanb[(size_t)r1 * HID + ks * 32 + kq];
      a[1][0][ks] = *(const s16x8*)&hb[(size_t)r0 * HID + ks * 32 + kq];
      a[1][1][ks] = *(const s16x8*)&hb[(size_t)r1 * HID + ks * 32 + kq];
    }
  }

  // stage both weight matrices: contiguous 16B per thread, coalesced
#pragma unroll
  for (int it = 0; it < 4; it++) {
    int o = (it * 512 + t) * 8;
    *(s16x8*)&ws[o] = *(const s16x8*)&WlS[o];
    *(s16x8*)&ws[16384 + o] = *(const s16x8*)&WrS[o];
  }
  __syncthreads();

  if (active) {
    f32x4 acc[2][8];
#pragma unroll
    for (int mt = 0; mt < 2; mt++)
#pragma unroll
      for (int nt = 0; nt < 8; nt++) acc[mt][nt] = (f32x4){0.f, 0.f, 0.f, 0.f};

#pragma unroll
    for (int half = 0; half < 2; half++) {
      const int hbase = half * 16384;
#pragma unroll
      for (int ks = 0; ks < 4; ks++)
#pragma unroll
        for (int nt = 0; nt < 8; nt++) {
          s16x8 bfrag = *(const s16x8*)&ws[hbase + ((ks * 8 + nt) * 64 + lane) * 8];
          acc[0][nt] = __builtin_amdgcn_mfma_f32_16x16x32_bf16(a[half][0][ks], bfrag, acc[0][nt], 0, 0, 0);
          acc[1][nt] = __builtin_amdgcn_mfma_f32_16x16x32_bf16(a[half][1][ks], bfrag, acc[1][nt], 0, 0, 0);
        }
    }

#pragma unroll
    for (int mt = 0; mt < 2; mt++) {
#pragma unroll
      for (int nt = 0; nt < 8; nt++) {
        int col = nt * 16 + l15;
        float bv = bias[col];
#pragma unroll
        for (int r = 0; r < 4; r++) {
          int row = rowBase + mt * 16 + quad * 4 + r;
          if (row < N) {
            float v = fmaxf(acc[mt][nt][r] + bv, 0.f);
            if (outIsBf16) outB[(size_t)row * HID + col] = f2bf(v);
            else           outF[(size_t)row * HID + col] = v;
          }
        }
      }
    }
  }
}

extern "C" void kernel_launch(void* const* d_in, const int* in_sizes, int n_in,
                              void* d_out, int out_size, void* d_ws, size_t ws_size,
                              hipStream_t stream) {
  const int* x = (const int*)d_in[0];
  const int* ei = (const int*)d_in[1];
  const float* emb = (const float*)d_in[2];
  const float* Wl1 = (const float*)d_in[3];
  const float* bl1 = (const float*)d_in[4];
  const float* Wr1 = (const float*)d_in[5];
  const float* Wl2 = (const float*)d_in[6];
  const float* bl2 = (const float*)d_in[7];
  const float* Wr2 = (const float*)d_in[8];
  float* out = (float*)d_out;

  const int N = in_sizes[0];
  const int E = in_sizes[1] / 2;
  const int* srcI = ei;
  const int* dstI = ei + E;

  // workspace layout (deg and partials CONTIGUOUS: one memset covers both)
  char* p = (char*)d_ws;
  ushort_t* hb = (ushort_t*)p;    p += (size_t)N * HID * sizeof(ushort_t);
  ushort_t* hb2 = (ushort_t*)p;   p += (size_t)N * HID * sizeof(ushort_t);
  ushort_t* meanb = (ushort_t*)p; p += (size_t)N * HID * sizeof(ushort_t);
  ushort_t* wb = (ushort_t*)p;    p += (size_t)4 * 16384 * sizeof(ushort_t);
  int* deg = (int*)p;             p += (size_t)((N + 3) & ~3) * sizeof(int);
  ull_t* partials = (ull_t*)p;    p += 128 * sizeof(ull_t);
  int* offsets = (int*)p;         p += (size_t)((N + 4) & ~3) * sizeof(int);
  int* cursor = (int*)p;          p += (size_t)((N + 3) & ~3) * sizeof(int);
  int* csr = (int*)p;             p += (size_t)((E + 3) & ~3) * sizeof(int);

  ushort_t* Wlb1 = wb;
  ushort_t* Wrb1 = wb + 16384;
  ushort_t* Wlb2 = wb + 32768;
  ushort_t* Wrb2 = wb + 49152;

  const int nScanBlocks = (N + 1023) / 1024;  // 98 <= 128 partial slots
  const int eBlocks = (E + 255) / 256;
  const int gemmBlocks = (N + 255) / 256;     // 512 threads, 256 rows/block
  const int aggBlocks = (N + 15) / 16;
  const int eN = (N + 7) / 8;
  const int prepBlocks = (eN * 16 + 65536 + E + 255) / 256;
  const size_t zeroBytes = (size_t)((N + 3) & ~3) * sizeof(int)
                         + 128 * sizeof(ull_t);

  // ---- CSR build + conversions (memset covers deg AND partials) ----
  hipMemsetAsync(deg, 0, zeroBytes, stream);
  prep_kernel<<<prepBlocks, 256, 0, stream>>>(emb, x, hb, N,
                                              Wl1, Wr1, Wl2, Wr2, wb,
                                              dstI, deg, E);
  scan_kernel<<<nScanBlocks, 256, 0, stream>>>(deg, offsets, cursor,
                                               partials, N, E);
  fill_kernel<<<eBlocks, 256, 0, stream>>>(srcI, dstI, cursor, csr, E);

  // ---- layer 1: hb -> hb2 (bf16) ----
  aggregate_kernel<<<aggBlocks, 256, 0, stream>>>(hb, offsets, csr, meanb, N);
  mfma_gemm_kernel<<<gemmBlocks, 512, 0, stream>>>(meanb, hb, Wlb1, Wrb1, bl1,
                                                   nullptr, hb2, N, 1);

  // ---- layer 2: hb2 -> out (f32) ----
  aggregate_kernel<<<aggBlocks, 256, 0, stream>>>(hb2, offsets, csr, meanb, N);
  mfma_gemm_kernel<<<gemmBlocks, 512, 0, stream>>>(meanb, hb2, Wlb2, Wrb2, bl2,
                                                   out, nullptr, N, 0);
}